// Round 4
// baseline (2300.596 us; speedup 1.0000x reference)
//
#include <hip/hip_runtime.h>
#include <math.h>

#define NN 50000
#define EE 800000
#define OO 4
#define CC 64
#define KDD 16
#define KEYDD 128
#define LCAP 64  // edges per chunk in mega (deg ~ Poisson(16), max ~45; chunk loop handles any deg)

__device__ __forceinline__ float wave_sum64(float v) {
  for (int off = 32; off > 0; off >>= 1) v += __shfl_xor(v, off, 64);
  return v;
}

// P0: Mrow[c1*64+c2] = sum_k keyW[k,c1]*qryW[k,c2]. 16 blocks; qryW (32KB) in LDS.
__global__ void prep_gt_kernel(const float* __restrict__ keyW, const float* __restrict__ qryW,
                               float* __restrict__ Mrow) {
  __shared__ float qw[KEYDD * CC];   // 32 KB
  __shared__ float kws[KEYDD * 4];   // 2 KB: keyW slice for this block's 4 c1 values
  int t = threadIdx.x, b = blockIdx.x;
  for (int i = t; i < KEYDD * CC; i += 256) qw[i] = qryW[i];
  for (int i = t; i < KEYDD * 4; i += 256) {
    int k = i >> 2, c1l = i & 3;
    kws[i] = keyW[k * CC + b * 4 + c1l];
  }
  __syncthreads();
  int c1l = t >> 6, c2 = t & 63;
  float s = 0.f;
  #pragma unroll 8
  for (int k = 0; k < KEYDD; ++k)
    s = fmaf(kws[k * 4 + c1l], qw[k * CC + c2], s);
  Mrow[(b * 4 + c1l) * CC + c2] = s;
}

// P1: aVec[c]=sum_k keyB[k]*qryW[k,c]; bVec[c]=sum_k qryB[k]*keyW[k,c]; c0=keyB.qryB;
// fk[p,o,c] = dot16(fkb[p,o,:], fkw[c,:])
__global__ void prep_rest_kernel(const float* __restrict__ keyW, const float* __restrict__ keyB,
                                 const float* __restrict__ qryW, const float* __restrict__ qryB,
                                 const float* __restrict__ fkb, const float* __restrict__ fkw,
                                 float* __restrict__ aVec, float* __restrict__ bVec,
                                 float* __restrict__ c0, float* __restrict__ fk) {
  int t = threadIdx.x;
  if (t < CC) {
    float sa = 0.f, sb = 0.f;
    for (int k = 0; k < KEYDD; ++k) {
      sa = fmaf(keyB[k], qryW[k * CC + t], sa);
      sb = fmaf(qryB[k], keyW[k * CC + t], sb);
    }
    aVec[t] = sa; bVec[t] = sb;
  }
  if (t == 0) {
    float s = 0.f;
    for (int k = 0; k < KEYDD; ++k) s = fmaf(keyB[k], qryB[k], s);
    c0[0] = s;
  }
  for (int idx = t; idx < OO * OO * CC; idx += 256) {
    int p = idx >> 8, rem = idx & 255;
    int o = rem >> 6, c = rem & 63;
    float s = 0.f;
    #pragma unroll
    for (int kd = 0; kd < KDD; ++kd)
      s = fmaf(fkb[(p * OO + o) * KDD + kd], fkw[c * KDD + kd], s);
    fk[idx] = s;
  }
}

// K1: ub[row,c] = sum_c2 M[c,c2]*x[row,c2] + bVec[c];  sA[row] = aVec . x[row,:]
__global__ void node_proj_kernel(const float* __restrict__ x, const float* __restrict__ Mrow,
                                 const float* __restrict__ aVec, const float* __restrict__ bVec,
                                 float* __restrict__ ub_g, float* __restrict__ sAt) {
  __shared__ float xs[4 * CC];
  int t = threadIdx.x, r = t >> 6, c = t & 63;
  size_t row = (size_t)blockIdx.x * 4 + r;
  float xv = x[row * CC + c];
  xs[t] = xv;
  __syncthreads();
  const float4* m4 = reinterpret_cast<const float4*>(Mrow + c * CC);
  const float4* xs4 = reinterpret_cast<const float4*>(&xs[r * CC]);
  float accv = 0.f;
  #pragma unroll
  for (int q = 0; q < 16; ++q) {
    float4 mm = m4[q];
    float4 xx = xs4[q];
    accv = fmaf(mm.x, xx.x, accv);
    accv = fmaf(mm.y, xx.y, accv);
    accv = fmaf(mm.z, xx.z, accv);
    accv = fmaf(mm.w, xx.w, accv);
  }
  ub_g[row * CC + c] = accv + bVec[c];
  float pa = wave_sum64(aVec[c] * xv);
  if (c == 0) sAt[row] = pa;
}

// K2a: CSR degree counts
__global__ void count_kernel(const int* __restrict__ ei, int* __restrict__ counts) {
  int e = blockIdx.x * 256 + threadIdx.x;
  if (e < EE) atomicAdd(&counts[ei[EE + e]], 1);
}

// K2b: single-block chunked exclusive scan
__global__ void scan_kernel(const int* __restrict__ counts, int* __restrict__ offsets, int n) {
  __shared__ int sums[1024];
  int t = threadIdx.x;
  int chunk = (n + 1023) >> 10;
  int begin = t * chunk;
  int finish = min(begin + chunk, n);
  int s = 0;
  for (int i = begin; i < finish; ++i) s += counts[i];
  sums[t] = s;
  __syncthreads();
  for (int off = 1; off < 1024; off <<= 1) {
    int v = sums[t];
    int w = (t >= off) ? sums[t - off] : 0;
    __syncthreads();
    sums[t] = v + w;
    __syncthreads();
  }
  int excl = (t == 0) ? 0 : sums[t - 1];
  for (int i = begin; i < finish; ++i) {
    offsets[i] = excl;
    excl += counts[i];
  }
  if (t == 1023) offsets[n] = excl;
}

// K2c: fill CSR edge list + src list; reuses counts as cursor (ends at 0).
__global__ void fill_kernel(const int* __restrict__ ei, const int* __restrict__ offsets,
                            int* __restrict__ counts, int* __restrict__ edge_list,
                            int* __restrict__ esrc) {
  int e = blockIdx.x * 256 + threadIdx.x;
  if (e < EE) {
    int d = ei[EE + e];
    int r = atomicSub(&counts[d], 1) - 1;
    int pos = offsets[d] + r;
    edge_list[pos] = e;
    esrc[pos] = ei[e];
  }
}

// K3: MEGA — per node, chunked two-phase softmax + aggregation + fiber mix.
// Phase 1 (lane=(og,c4), wave=edge-stride): logits via float4 + 16-lane reduce -> LDS.
// Phase 3 (wave=o, lane=c): exp vs final chunk max, kv from LDS-staged kb, aggregate.
__global__ __launch_bounds__(256, 8) void mega_kernel(
    const float* __restrict__ x, const float* __restrict__ ub_g,
    const float* __restrict__ sAt, const float* __restrict__ c0p,
    const float* __restrict__ kb, const float* __restrict__ kW,
    const int* __restrict__ offsets, const int* __restrict__ edge_list,
    const int* __restrict__ esrc, const float* __restrict__ fkg,
    const float* __restrict__ bias, float* __restrict__ out) {
  __shared__ float kbL[LCAP * 64];     // 16 KB: kb rows for chunk, [j][o*16+kd]
  __shared__ float logitL[LCAP * OO];  // 1 KB
  __shared__ int srcL[LCAP];
  __shared__ float mmaxS[16];          // [wave][og]
  __shared__ float x1[OO * CC];
  int n = blockIdx.x;
  int t = threadIdx.x;
  int wave = t >> 6, lane = t & 63;
  int og = lane >> 4, c4 = lane & 15;
  const float scale = 0.08838834764831845f;  // 1/sqrt(128)
  int js = offsets[n], je = offsets[n + 1];
  int deg = je - js;

  // per-thread constants
  float4 ub4 = *reinterpret_cast<const float4*>(ub_g + (size_t)n * (OO * CC) + og * CC + c4 * 4);
  float base_og = (sAt[n * OO + og] + c0p[0]) * scale;
  const float4* kwp = reinterpret_cast<const float4*>(kW + lane * KDD);
  float4 kw0 = kwp[0], kw1 = kwp[1], kw2 = kwp[2], kw3 = kwp[3];

  float m = -3.4e38f, S = 0.f, acc = 0.f;

  for (int cs = 0; cs < deg; cs += LCAP) {
    int cl = min(LCAP, deg - cs);
    __syncthreads();  // previous chunk's phase-3 readers done
    if (t < cl) srcL[t] = esrc[js + cs + t];
    __syncthreads();
    // stage kb rows (coalesced 256B-per-edge gather) into LDS
    for (int i = t; i < cl * 64; i += 256) {
      int e = edge_list[js + cs + (i >> 6)];
      kbL[i] = kb[(size_t)e * (OO * KDD) + (i & 63)];
    }
    // phase 1: logits, edges strided across waves
    float wm = -3.4e38f;
    for (int j = wave; j < cl; j += 4) {
      int s = srcL[j];
      float4 xv = *reinterpret_cast<const float4*>(x + (size_t)s * (OO * CC) + og * CC + c4 * 4);
      float p = xv.x * ub4.x + xv.y * ub4.y + xv.z * ub4.z + xv.w * ub4.w;
      p += __shfl_xor(p, 1, 64);
      p += __shfl_xor(p, 2, 64);
      p += __shfl_xor(p, 4, 64);
      p += __shfl_xor(p, 8, 64);
      float l = fmaf(p, scale, base_og);
      wm = fmaxf(wm, l);
      if (c4 == 0) logitL[j * OO + og] = l;
    }
    if (c4 == 0) mmaxS[wave * OO + og] = wm;
    __syncthreads();  // kbL, logitL, mmaxS visible
    // chunk max for this wave's o, merged online with previous chunks
    float cm = fmaxf(fmaxf(mmaxS[0 * OO + wave], mmaxS[1 * OO + wave]),
                     fmaxf(mmaxS[2 * OO + wave], mmaxS[3 * OO + wave]));
    float mnew = fmaxf(m, cm);
    float rsc = __expf(m - mnew);  // first chunk: exp(-inf)=0
    S *= rsc; acc *= rsc; m = mnew;
    // phase 3: aggregation (wave = o, lane = c)
    int sP = 0; float xvP = 0.f;
    if (cl > 0) { sP = srcL[0]; xvP = x[(size_t)sP * (OO * CC) + t]; }
    for (int j = 0; j < cl; ++j) {
      float xvc = xvP;
      if (j + 1 < cl) { int s1 = srcL[j + 1]; xvP = x[(size_t)s1 * (OO * CC) + t]; }
      float l = logitL[j * OO + wave];
      float ev = __expf(l - m);
      S += ev;
      const float4* bp = reinterpret_cast<const float4*>(&kbL[j * 64 + wave * KDD]);
      float4 b0 = bp[0], b1 = bp[1], b2 = bp[2], b3 = bp[3];
      float kva = 0.f, kvb = 0.f;
      kva = fmaf(b0.x, kw0.x, kva); kva = fmaf(b0.y, kw0.y, kva);
      kva = fmaf(b0.z, kw0.z, kva); kva = fmaf(b0.w, kw0.w, kva);
      kva = fmaf(b1.x, kw1.x, kva); kva = fmaf(b1.y, kw1.y, kva);
      kva = fmaf(b1.z, kw1.z, kva); kva = fmaf(b1.w, kw1.w, kva);
      kvb = fmaf(b2.x, kw2.x, kvb); kvb = fmaf(b2.y, kw2.y, kvb);
      kvb = fmaf(b2.z, kw2.z, kvb); kvb = fmaf(b2.w, kw2.w, kvb);
      kvb = fmaf(b3.x, kw3.x, kvb); kvb = fmaf(b3.y, kw3.y, kvb);
      kvb = fmaf(b3.w, kw3.w, kvb); kvb = fmaf(b3.z, kw3.z, kvb);
      acc = fmaf(ev * (kva + kvb), xvc, acc);
    }
  }
  float invd = 1.0f / (S + 1e-6f);
  x1[t] = acc * invd;
  __syncthreads();
  // fiber mix: out[n,p=wave,c] = 0.25 * sum_oo x1[oo,c]*fk[wave,oo,c] + bias[c]
  float s2s = 0.f;
  #pragma unroll
  for (int oo = 0; oo < OO; ++oo)
    s2s = fmaf(x1[oo * CC + lane], fkg[wave * (OO * CC) + oo * CC + lane], s2s);
  out[(size_t)n * (OO * CC) + t] = 0.25f * s2s + bias[lane];
}

extern "C" void kernel_launch(void* const* d_in, const int* in_sizes, int n_in,
                              void* d_out, int out_size, void* d_ws, size_t ws_size,
                              hipStream_t stream) {
  const float* x    = (const float*)d_in[0];
  const float* kb   = (const float*)d_in[1];
  const float* fkb  = (const float*)d_in[2];
  const int*   ei   = (const int*)d_in[3];
  const float* kW   = (const float*)d_in[4];
  const float* fkW  = (const float*)d_in[5];
  const float* keyW = (const float*)d_in[6];
  const float* keyB = (const float*)d_in[7];
  const float* qryW = (const float*)d_in[8];
  const float* qryB = (const float*)d_in[9];
  const float* bias = (const float*)d_in[10];
  float* out = (float*)d_out;

  float* wsf  = (float*)d_ws;
  float* Mrow = wsf;                          // 4096
  float* aVec = Mrow + 4096;                  // 64
  float* bVec = aVec + 64;                    // 64
  float* c0   = bVec + 64;                    // 1 (+63 pad)
  float* fk   = c0 + 64;                      // 1024
  float* ub_g = fk + 1024;                    // 12.8M
  float* sAt  = ub_g + (size_t)NN * OO * CC;  // 200000
  int* counts    = (int*)(sAt + NN * OO);     // 50000
  int* offsets   = counts + NN;               // 50001
  int* edge_list = offsets + NN + 1;          // 800000
  int* esrc      = edge_list + EE;            // 800000

  hipMemsetAsync(counts, 0, (size_t)NN * sizeof(int), stream);

  prep_gt_kernel<<<16, 256, 0, stream>>>(keyW, qryW, Mrow);
  prep_rest_kernel<<<1, 256, 0, stream>>>(keyW, keyB, qryW, qryB, fkb, fkW, aVec, bVec, c0, fk);
  count_kernel<<<(EE + 255) / 256, 256, 0, stream>>>(ei, counts);
  scan_kernel<<<1, 1024, 0, stream>>>(counts, offsets, NN);
  fill_kernel<<<(EE + 255) / 256, 256, 0, stream>>>(ei, offsets, counts, edge_list, esrc);
  node_proj_kernel<<<NN, 256, 0, stream>>>(x, Mrow, aVec, bVec, ub_g, sAt);
  mega_kernel<<<NN, 256, 0, stream>>>(x, ub_g, sAt, c0, kb, kW, offsets, edge_list, esrc,
                                      fk, bias, out);
}

// Round 5
// 926.016 us; speedup vs baseline: 2.4844x; 2.4844x over previous
//
#include <hip/hip_runtime.h>
#include <math.h>

#define NN 50000
#define EE 800000
#define OO 4
#define CC 64
#define KDD 16
#define KEYDD 128
#define LCAP 64  // edges per chunk in mega; chunk loop handles any degree

__device__ __forceinline__ float wave_sum64(float v) {
  for (int off = 32; off > 0; off >>= 1) v += __shfl_xor(v, off, 64);
  return v;
}

// P0 (blocks 0..15): Mt[c2*64+c1] = sum_k keyW[k,c1]*qryW[k,c2]  (TRANSPOSED for
// coalesced node_proj reads). Block 16: aVec/bVec/c0/fk.
__global__ void prep_kernel(const float* __restrict__ keyW, const float* __restrict__ keyB,
                            const float* __restrict__ qryW, const float* __restrict__ qryB,
                            const float* __restrict__ fkb, const float* __restrict__ fkw,
                            float* __restrict__ Mt, float* __restrict__ aVec,
                            float* __restrict__ bVec, float* __restrict__ c0,
                            float* __restrict__ fk) {
  __shared__ float qw[KEYDD * CC];   // 32 KB
  __shared__ float kws[KEYDD * 4];   // 2 KB
  int t = threadIdx.x, b = blockIdx.x;
  if (b < 16) {
    for (int i = t; i < KEYDD * CC; i += 256) qw[i] = qryW[i];
    for (int i = t; i < KEYDD * 4; i += 256) {
      int k = i >> 2, c1l = i & 3;
      kws[i] = keyW[k * CC + b * 4 + c1l];
    }
    __syncthreads();
    int c1l = t >> 6, c2 = t & 63;
    float s = 0.f;
    #pragma unroll 8
    for (int k = 0; k < KEYDD; ++k)
      s = fmaf(kws[k * 4 + c1l], qw[k * CC + c2], s);
    Mt[c2 * CC + b * 4 + c1l] = s;
  } else {
    if (t < CC) {
      float sa = 0.f, sb = 0.f;
      for (int k = 0; k < KEYDD; ++k) {
        sa = fmaf(keyB[k], qryW[k * CC + t], sa);
        sb = fmaf(qryB[k], keyW[k * CC + t], sb);
      }
      aVec[t] = sa; bVec[t] = sb;
    }
    if (t == 0) {
      float s = 0.f;
      for (int k = 0; k < KEYDD; ++k) s = fmaf(keyB[k], qryB[k], s);
      c0[0] = s;
    }
    for (int idx = t; idx < OO * OO * CC; idx += 256) {
      int p = idx >> 8, rem = idx & 255;
      int o = rem >> 6, c = rem & 63;
      float s = 0.f;
      #pragma unroll
      for (int kd = 0; kd < KDD; ++kd)
        s = fmaf(fkb[(p * OO + o) * KDD + kd], fkw[c * KDD + kd], s);
      fk[idx] = s;
    }
  }
}

// K1: ub[row,c] = sum_c2 Mt[c2,c]*x[row,c2] + bVec[c];  sA[row] = aVec . x[row,:]
// Mt reads are coalesced 256B segments, L1-resident across blocks.
__global__ void node_proj_kernel(const float* __restrict__ x, const float* __restrict__ Mt,
                                 const float* __restrict__ aVec, const float* __restrict__ bVec,
                                 float* __restrict__ ub_g, float* __restrict__ sAt) {
  __shared__ float xs[4 * CC];
  int t = threadIdx.x, r = t >> 6, c = t & 63;
  size_t row = (size_t)blockIdx.x * 4 + r;
  float xv = x[row * CC + c];
  xs[t] = xv;
  __syncthreads();
  const float* xr = &xs[r * CC];
  float accv = 0.f;
  #pragma unroll 8
  for (int c2 = 0; c2 < CC; ++c2)
    accv = fmaf(Mt[c2 * CC + c], xr[c2], accv);
  ub_g[row * CC + c] = accv + bVec[c];
  float pa = wave_sum64(aVec[c] * xv);
  if (c == 0) sAt[row] = pa;
}

// K2a: CSR degree counts
__global__ void count_kernel(const int* __restrict__ ei, int* __restrict__ counts) {
  int e = blockIdx.x * 256 + threadIdx.x;
  if (e < EE) atomicAdd(&counts[ei[EE + e]], 1);
}

// K2b: single-block chunked exclusive scan
__global__ void scan_kernel(const int* __restrict__ counts, int* __restrict__ offsets, int n) {
  __shared__ int sums[1024];
  int t = threadIdx.x;
  int chunk = (n + 1023) >> 10;
  int begin = t * chunk;
  int finish = min(begin + chunk, n);
  int s = 0;
  for (int i = begin; i < finish; ++i) s += counts[i];
  sums[t] = s;
  __syncthreads();
  for (int off = 1; off < 1024; off <<= 1) {
    int v = sums[t];
    int w = (t >= off) ? sums[t - off] : 0;
    __syncthreads();
    sums[t] = v + w;
    __syncthreads();
  }
  int excl = (t == 0) ? 0 : sums[t - 1];
  for (int i = begin; i < finish; ++i) {
    offsets[i] = excl;
    excl += counts[i];
  }
  if (t == 1023) offsets[n] = excl;
}

// K2c: fill CSR edge list + src list; reuses counts as cursor (ends at 0).
__global__ void fill_kernel(const int* __restrict__ ei, const int* __restrict__ offsets,
                            int* __restrict__ counts, int* __restrict__ edge_list,
                            int* __restrict__ esrc) {
  int e = blockIdx.x * 256 + threadIdx.x;
  if (e < EE) {
    int d = ei[EE + e];
    int r = atomicSub(&counts[d], 1) - 1;
    int pos = offsets[d] + r;
    edge_list[pos] = e;
    esrc[pos] = ei[e];
  }
}

// K3: MEGA — per node, chunked two-phase softmax + aggregation + fiber mix.
// Phase 1 (lane=(og,c4), wave=edge-stride): logits via float4 + 16-lane reduce -> LDS.
// Phase 3 (wave=o, lane=c): exp vs merged max, kv from LDS-staged kb, aggregate.
// NOTE: no min-waves launch_bounds — (256,8) capped VGPRs at 64 and spilled
// the loop-carried float4s to scratch (R4: 3.9GB FETCH + 3.8GB WRITE of spill
// traffic, 4x regression). LDS (18.9KB) limits occupancy to 8 blocks/CU anyway.
__global__ __launch_bounds__(256) void mega_kernel(
    const float* __restrict__ x, const float* __restrict__ ub_g,
    const float* __restrict__ sAt, const float* __restrict__ c0p,
    const float* __restrict__ kb, const float* __restrict__ kW,
    const int* __restrict__ offsets, const int* __restrict__ edge_list,
    const int* __restrict__ esrc, const float* __restrict__ fkg,
    const float* __restrict__ bias, float* __restrict__ out) {
  __shared__ float kbL[LCAP * 64];     // 16 KB: kb rows for chunk, [j][o*16+kd]
  __shared__ float logitL[LCAP * OO];  // 1 KB
  __shared__ int srcL[LCAP];
  __shared__ float mmaxS[16];          // [wave][og]
  __shared__ float x1[OO * CC];
  int n = blockIdx.x;
  int t = threadIdx.x;
  int wave = t >> 6, lane = t & 63;
  int og = lane >> 4, c4 = lane & 15;
  const float scale = 0.08838834764831845f;  // 1/sqrt(128)
  int js = offsets[n], je = offsets[n + 1];
  int deg = je - js;

  // per-thread constants
  float4 ub4 = *reinterpret_cast<const float4*>(ub_g + (size_t)n * (OO * CC) + og * CC + c4 * 4);
  float base_og = (sAt[n * OO + og] + c0p[0]) * scale;
  const float4* kwp = reinterpret_cast<const float4*>(kW + lane * KDD);
  float4 kw0 = kwp[0], kw1 = kwp[1], kw2 = kwp[2], kw3 = kwp[3];

  float m = -3.4e38f, S = 0.f, acc = 0.f;

  for (int cs = 0; cs < deg; cs += LCAP) {
    int cl = min(LCAP, deg - cs);
    __syncthreads();  // previous chunk's phase-3 readers done
    if (t < cl) srcL[t] = esrc[js + cs + t];
    __syncthreads();
    // stage kb rows (256B-per-edge gather) into LDS
    for (int i = t; i < cl * 64; i += 256) {
      int e = edge_list[js + cs + (i >> 6)];
      kbL[i] = kb[(size_t)e * (OO * KDD) + (i & 63)];
    }
    // phase 1: logits, edges strided across waves
    float wm = -3.4e38f;
    for (int j = wave; j < cl; j += 4) {
      int s = srcL[j];
      float4 xv = *reinterpret_cast<const float4*>(x + (size_t)s * (OO * CC) + og * CC + c4 * 4);
      float p = xv.x * ub4.x + xv.y * ub4.y + xv.z * ub4.z + xv.w * ub4.w;
      p += __shfl_xor(p, 1, 64);
      p += __shfl_xor(p, 2, 64);
      p += __shfl_xor(p, 4, 64);
      p += __shfl_xor(p, 8, 64);
      float l = fmaf(p, scale, base_og);
      wm = fmaxf(wm, l);
      if (c4 == 0) logitL[j * OO + og] = l;
    }
    if (c4 == 0) mmaxS[wave * OO + og] = wm;
    __syncthreads();  // kbL, logitL, mmaxS visible
    // chunk max for this wave's o, merged online with previous chunks
    float cm = fmaxf(fmaxf(mmaxS[0 * OO + wave], mmaxS[1 * OO + wave]),
                     fmaxf(mmaxS[2 * OO + wave], mmaxS[3 * OO + wave]));
    float mnew = fmaxf(m, cm);
    float rsc = __expf(m - mnew);  // first chunk: exp(-inf)=0
    S *= rsc; acc *= rsc; m = mnew;
    // phase 3: aggregation (wave = o, lane = c)
    int sP = srcL[0];
    float xvP = x[(size_t)sP * (OO * CC) + t];
    for (int j = 0; j < cl; ++j) {
      float xvc = xvP;
      if (j + 1 < cl) { int s1 = srcL[j + 1]; xvP = x[(size_t)s1 * (OO * CC) + t]; }
      float l = logitL[j * OO + wave];
      float ev = __expf(l - m);
      S += ev;
      const float4* bp = reinterpret_cast<const float4*>(&kbL[j * 64 + wave * KDD]);
      float4 b0 = bp[0], b1 = bp[1], b2 = bp[2], b3 = bp[3];
      float kva = 0.f, kvb = 0.f;
      kva = fmaf(b0.x, kw0.x, kva); kva = fmaf(b0.y, kw0.y, kva);
      kva = fmaf(b0.z, kw0.z, kva); kva = fmaf(b0.w, kw0.w, kva);
      kva = fmaf(b1.x, kw1.x, kva); kva = fmaf(b1.y, kw1.y, kva);
      kva = fmaf(b1.z, kw1.z, kva); kva = fmaf(b1.w, kw1.w, kva);
      kvb = fmaf(b2.x, kw2.x, kvb); kvb = fmaf(b2.y, kw2.y, kvb);
      kvb = fmaf(b2.z, kw2.z, kvb); kvb = fmaf(b2.w, kw2.w, kvb);
      kvb = fmaf(b3.x, kw3.x, kvb); kvb = fmaf(b3.y, kw3.y, kvb);
      kvb = fmaf(b3.z, kw3.z, kvb); kvb = fmaf(b3.w, kw3.w, kvb);
      acc = fmaf(ev * (kva + kvb), xvc, acc);
    }
  }
  float invd = 1.0f / (S + 1e-6f);
  x1[t] = acc * invd;
  __syncthreads();
  // fiber mix: out[n,p=wave,c] = 0.25 * sum_oo x1[oo,c]*fk[wave,oo,c] + bias[c]
  float s2s = 0.f;
  #pragma unroll
  for (int oo = 0; oo < OO; ++oo)
    s2s = fmaf(x1[oo * CC + lane], fkg[wave * (OO * CC) + oo * CC + lane], s2s);
  out[(size_t)n * (OO * CC) + t] = 0.25f * s2s + bias[lane];
}

extern "C" void kernel_launch(void* const* d_in, const int* in_sizes, int n_in,
                              void* d_out, int out_size, void* d_ws, size_t ws_size,
                              hipStream_t stream) {
  const float* x    = (const float*)d_in[0];
  const float* kb   = (const float*)d_in[1];
  const float* fkb  = (const float*)d_in[2];
  const int*   ei   = (const int*)d_in[3];
  const float* kW   = (const float*)d_in[4];
  const float* fkW  = (const float*)d_in[5];
  const float* keyW = (const float*)d_in[6];
  const float* keyB = (const float*)d_in[7];
  const float* qryW = (const float*)d_in[8];
  const float* qryB = (const float*)d_in[9];
  const float* bias = (const float*)d_in[10];
  float* out = (float*)d_out;

  float* wsf  = (float*)d_ws;
  float* Mt   = wsf;                          // 4096
  float* aVec = Mt + 4096;                    // 64
  float* bVec = aVec + 64;                    // 64
  float* c0   = bVec + 64;                    // 1 (+63 pad)
  float* fk   = c0 + 64;                      // 1024
  float* ub_g = fk + 1024;                    // 12.8M
  float* sAt  = ub_g + (size_t)NN * OO * CC;  // 200000
  int* counts    = (int*)(sAt + NN * OO);     // 50000
  int* offsets   = counts + NN;               // 50001
  int* edge_list = offsets + NN + 1;          // 800000
  int* esrc      = edge_list + EE;            // 800000

  hipMemsetAsync(counts, 0, (size_t)NN * sizeof(int), stream);

  prep_kernel<<<17, 256, 0, stream>>>(keyW, keyB, qryW, qryB, fkb, fkW, Mt, aVec, bVec, c0, fk);
  count_kernel<<<(EE + 255) / 256, 256, 0, stream>>>(ei, counts);
  scan_kernel<<<1, 1024, 0, stream>>>(counts, offsets, NN);
  fill_kernel<<<(EE + 255) / 256, 256, 0, stream>>>(ei, offsets, counts, edge_list, esrc);
  node_proj_kernel<<<NN, 256, 0, stream>>>(x, Mt, aVec, bVec, ub_g, sAt);
  mega_kernel<<<NN, 256, 0, stream>>>(x, ub_g, sAt, c0, kb, kW, offsets, edge_list, esrc,
                                      fk, bias, out);
}

// Round 6
// 677.283 us; speedup vs baseline: 3.3968x; 1.3673x over previous
//
#include <hip/hip_runtime.h>
#include <math.h>

#define NN 50000
#define EE 800000
#define OO 4
#define CC 64
#define KDD 16
#define KEYDD 128
#define CH 8  // unrolled edges per chunk in mega (MLP depth; arrays fully unrolled)

__device__ __forceinline__ float wave_sum64(float v) {
  for (int off = 32; off > 0; off >>= 1) v += __shfl_xor(v, off, 64);
  return v;
}

// P0 (blocks 0..15): Mt[c2*64+c1] = sum_k keyW[k,c1]*qryW[k,c2]  (TRANSPOSED for
// coalesced node_proj reads). Block 16: aVec/bVec/c0/fk (fk pre-scaled by 0.25).
__global__ void prep_kernel(const float* __restrict__ keyW, const float* __restrict__ keyB,
                            const float* __restrict__ qryW, const float* __restrict__ qryB,
                            const float* __restrict__ fkb, const float* __restrict__ fkw,
                            float* __restrict__ Mt, float* __restrict__ aVec,
                            float* __restrict__ bVec, float* __restrict__ c0,
                            float* __restrict__ fk) {
  __shared__ float qw[KEYDD * CC];   // 32 KB
  __shared__ float kws[KEYDD * 4];   // 2 KB
  int t = threadIdx.x, b = blockIdx.x;
  if (b < 16) {
    for (int i = t; i < KEYDD * CC; i += 256) qw[i] = qryW[i];
    for (int i = t; i < KEYDD * 4; i += 256) {
      int k = i >> 2, c1l = i & 3;
      kws[i] = keyW[k * CC + b * 4 + c1l];
    }
    __syncthreads();
    int c1l = t >> 6, c2 = t & 63;
    float s = 0.f;
    #pragma unroll 8
    for (int k = 0; k < KEYDD; ++k)
      s = fmaf(kws[k * 4 + c1l], qw[k * CC + c2], s);
    Mt[c2 * CC + b * 4 + c1l] = s;
  } else {
    if (t < CC) {
      float sa = 0.f, sb = 0.f;
      for (int k = 0; k < KEYDD; ++k) {
        sa = fmaf(keyB[k], qryW[k * CC + t], sa);
        sb = fmaf(qryB[k], keyW[k * CC + t], sb);
      }
      aVec[t] = sa; bVec[t] = sb;
    }
    if (t == 0) {
      float s = 0.f;
      for (int k = 0; k < KEYDD; ++k) s = fmaf(keyB[k], qryB[k], s);
      c0[0] = s;
    }
    for (int idx = t; idx < OO * OO * CC; idx += 256) {
      int p = idx >> 8, rem = idx & 255;
      int o = rem >> 6, c = rem & 63;
      float s = 0.f;
      #pragma unroll
      for (int kd = 0; kd < KDD; ++kd)
        s = fmaf(fkb[(p * OO + o) * KDD + kd], fkw[c * KDD + kd], s);
      fk[idx] = 0.25f * s;  // fold the 1/O normalization here
    }
  }
}

// K1: ub[row,c] = sum_c2 Mt[c2,c]*x[row,c2] + bVec[c];
// sAt[row] = (aVec.x[row,:] + c0) * scale  (pre-folded for mega)
__global__ void node_proj_kernel(const float* __restrict__ x, const float* __restrict__ Mt,
                                 const float* __restrict__ aVec, const float* __restrict__ bVec,
                                 const float* __restrict__ c0p,
                                 float* __restrict__ ub_g, float* __restrict__ sAt) {
  __shared__ float xs[4 * CC];
  int t = threadIdx.x, r = t >> 6, c = t & 63;
  size_t row = (size_t)blockIdx.x * 4 + r;
  float xv = x[row * CC + c];
  xs[t] = xv;
  __syncthreads();
  const float* xr = &xs[r * CC];
  float accv = 0.f;
  #pragma unroll 8
  for (int c2 = 0; c2 < CC; ++c2)
    accv = fmaf(Mt[c2 * CC + c], xr[c2], accv);
  ub_g[row * CC + c] = accv + bVec[c];
  float pa = wave_sum64(aVec[c] * xv);
  const float scale = 0.08838834764831845f;  // 1/sqrt(128)
  if (c == 0) sAt[row] = (pa + c0p[0]) * scale;
}

// K2a: CSR degree counts
__global__ void count_kernel(const int* __restrict__ ei, int* __restrict__ counts) {
  int e = blockIdx.x * 256 + threadIdx.x;
  if (e < EE) atomicAdd(&counts[ei[EE + e]], 1);
}

// K2b: single-block chunked exclusive scan
__global__ void scan_kernel(const int* __restrict__ counts, int* __restrict__ offsets, int n) {
  __shared__ int sums[1024];
  int t = threadIdx.x;
  int chunk = (n + 1023) >> 10;
  int begin = t * chunk;
  int finish = min(begin + chunk, n);
  int s = 0;
  for (int i = begin; i < finish; ++i) s += counts[i];
  sums[t] = s;
  __syncthreads();
  for (int off = 1; off < 1024; off <<= 1) {
    int v = sums[t];
    int w = (t >= off) ? sums[t - off] : 0;
    __syncthreads();
    sums[t] = v + w;
    __syncthreads();
  }
  int excl = (t == 0) ? 0 : sums[t - 1];
  for (int i = begin; i < finish; ++i) {
    offsets[i] = excl;
    excl += counts[i];
  }
  if (t == 1023) offsets[n] = excl;
}

// K2c: fill CSR edge list + src list; reuses counts as cursor (ends at 0).
__global__ void fill_kernel(const int* __restrict__ ei, const int* __restrict__ offsets,
                            int* __restrict__ counts, int* __restrict__ edge_list,
                            int* __restrict__ esrc) {
  int e = blockIdx.x * 256 + threadIdx.x;
  if (e < EE) {
    int d = ei[EE + e];
    int r = atomicSub(&counts[d], 1) - 1;
    int pos = offsets[d] + r;
    edge_list[pos] = e;
    esrc[pos] = ei[e];
  }
}

// K3: MEGA — per node; wave = o owns its (n,o) softmax+aggregation END-TO-END:
// no cross-wave traffic, NO barriers in the edge loop. 8-edge unrolled chunks:
// 8 independent x-row gathers in flight; the SAME xv register feeds both the
// logit dot and the message (round-5 gathered x twice). kb slices read via
// readfirstlane'd uniform offset (scalar-path loads, overlap VMEM). Per-chunk
// max merged online across chunks (exact same math as R5, absmax 0.0156).
// NOTE: no min-waves launch_bounds — (256,8) capped VGPRs at 64 and spilled
// (R4: 3.9GB FETCH + 3.8GB WRITE of spill traffic, 4x regression).
__global__ __launch_bounds__(256) void mega_kernel(
    const float* __restrict__ x, const float* __restrict__ ub_g,
    const float* __restrict__ sAt, const float* __restrict__ kb,
    const float* __restrict__ kW, const int* __restrict__ offsets,
    const int* __restrict__ edge_list, const int* __restrict__ esrc,
    const float* __restrict__ fkg, const float* __restrict__ bias,
    float* __restrict__ out) {
  __shared__ float x1[OO * CC];
  int n = blockIdx.x;
  int t = threadIdx.x;
  int o = t >> 6, c = t & 63;
  const float scale = 0.08838834764831845f;  // 1/sqrt(128)
  int js = offsets[n], je = offsets[n + 1];
  int deg = je - js;

  float ubr = ub_g[(size_t)n * (OO * CC) + t];
  float base = sAt[n * OO + o];  // (sA + c0) * scale, pre-folded
  const float4* kwp = reinterpret_cast<const float4*>(kW + c * KDD);
  float4 kw0 = kwp[0], kw1 = kwp[1], kw2 = kwp[2], kw3 = kwp[3];

  float m = -INFINITY, S = 0.f, acc = 0.f;
  int lane8 = c & 7;

  for (int cs = 0; cs < deg; cs += CH) {
    int cl = min(CH, deg - cs);
    // coalesced fetch of this chunk's edge ids / srcs (8-fold lane redundancy)
    int q = js + cs + min(lane8, cl - 1);
    int e_l = edge_list[q];
    int s_l = esrc[q];
    float xv[CH], lg[CH], kv[CH];
    // 1) issue all 8 x-row gathers (independent -> 8 outstanding VMEM loads)
    #pragma unroll
    for (int j = 0; j < CH; ++j) {
      int sj = __shfl(s_l, j, 64);
      xv[j] = x[(size_t)(sj * OO + o) * CC + c];
    }
    // 2) kb slices via wave-uniform (scalar) loads + dot with register kW row
    #pragma unroll
    for (int j = 0; j < CH; ++j) {
      int ej = __shfl(e_l, j, 64);
      int off = __builtin_amdgcn_readfirstlane(ej * (OO * KDD) + o * KDD);
      const float4* bp = reinterpret_cast<const float4*>(kb + off);
      float4 b0 = bp[0], b1 = bp[1], b2 = bp[2], b3 = bp[3];
      float kva = 0.f, kvb = 0.f;
      kva = fmaf(b0.x, kw0.x, kva); kva = fmaf(b0.y, kw0.y, kva);
      kva = fmaf(b0.z, kw0.z, kva); kva = fmaf(b0.w, kw0.w, kva);
      kva = fmaf(b1.x, kw1.x, kva); kva = fmaf(b1.y, kw1.y, kva);
      kva = fmaf(b1.z, kw1.z, kva); kva = fmaf(b1.w, kw1.w, kva);
      kvb = fmaf(b2.x, kw2.x, kvb); kvb = fmaf(b2.y, kw2.y, kvb);
      kvb = fmaf(b2.z, kw2.z, kvb); kvb = fmaf(b2.w, kw2.w, kvb);
      kvb = fmaf(b3.x, kw3.x, kvb); kvb = fmaf(b3.y, kw3.y, kvb);
      kvb = fmaf(b3.z, kw3.z, kvb); kvb = fmaf(b3.w, kw3.w, kvb);
      kv[j] = kva + kvb;
    }
    // 3) logits: full-wave reduce of xv . ubr  (tail lanes -> -inf)
    #pragma unroll
    for (int j = 0; j < CH; ++j) {
      float p = wave_sum64(xv[j] * ubr);
      lg[j] = (j < cl) ? fmaf(p, scale, base) : -INFINITY;
    }
    // 4) chunk max, online merge
    float cm = lg[0];
    #pragma unroll
    for (int j = 1; j < CH; ++j) cm = fmaxf(cm, lg[j]);
    float mn = fmaxf(m, cm);
    float rsc = __expf(m - mn);  // first chunk: exp(-inf)=0
    S *= rsc; acc *= rsc; m = mn;
    // 5) exp + aggregate (tail: ev = exp(-inf) = 0)
    #pragma unroll
    for (int j = 0; j < CH; ++j) {
      float ev = __expf(lg[j] - m);
      S += ev;
      acc = fmaf(ev * kv[j], xv[j], acc);
    }
  }
  float invd = 1.0f / (S + 1e-6f);
  x1[t] = acc * invd;
  __syncthreads();
  // fiber mix: out[n,p=o,c] = sum_oo x1[oo,c]*fk[o,oo,c] + bias[c]  (0.25 in fk)
  float s2s = 0.f;
  #pragma unroll
  for (int oo = 0; oo < OO; ++oo)
    s2s = fmaf(x1[oo * CC + c], fkg[o * (OO * CC) + oo * CC + c], s2s);
  out[(size_t)n * (OO * CC) + t] = s2s + bias[c];
}

extern "C" void kernel_launch(void* const* d_in, const int* in_sizes, int n_in,
                              void* d_out, int out_size, void* d_ws, size_t ws_size,
                              hipStream_t stream) {
  const float* x    = (const float*)d_in[0];
  const float* kb   = (const float*)d_in[1];
  const float* fkb  = (const float*)d_in[2];
  const int*   ei   = (const int*)d_in[3];
  const float* kW   = (const float*)d_in[4];
  const float* fkW  = (const float*)d_in[5];
  const float* keyW = (const float*)d_in[6];
  const float* keyB = (const float*)d_in[7];
  const float* qryW = (const float*)d_in[8];
  const float* qryB = (const float*)d_in[9];
  const float* bias = (const float*)d_in[10];
  float* out = (float*)d_out;

  float* wsf  = (float*)d_ws;
  float* Mt   = wsf;                          // 4096
  float* aVec = Mt + 4096;                    // 64
  float* bVec = aVec + 64;                    // 64
  float* c0   = bVec + 64;                    // 1 (+63 pad)
  float* fk   = c0 + 64;                      // 1024
  float* ub_g = fk + 1024;                    // 12.8M
  float* sAt  = ub_g + (size_t)NN * OO * CC;  // 200000
  int* counts    = (int*)(sAt + NN * OO);     // 50000
  int* offsets   = counts + NN;               // 50001
  int* edge_list = offsets + NN + 1;          // 800000
  int* esrc      = edge_list + EE;            // 800000

  hipMemsetAsync(counts, 0, (size_t)NN * sizeof(int), stream);

  prep_kernel<<<17, 256, 0, stream>>>(keyW, keyB, qryW, qryB, fkb, fkW, Mt, aVec, bVec, c0, fk);
  count_kernel<<<(EE + 255) / 256, 256, 0, stream>>>(ei, counts);
  scan_kernel<<<1, 1024, 0, stream>>>(counts, offsets, NN);
  fill_kernel<<<(EE + 255) / 256, 256, 0, stream>>>(ei, offsets, counts, edge_list, esrc);
  node_proj_kernel<<<NN, 256, 0, stream>>>(x, Mt, aVec, bVec, c0, ub_g, sAt);
  mega_kernel<<<NN, 256, 0, stream>>>(x, ub_g, sAt, kb, kW, offsets, edge_list, esrc,
                                      fk, bias, out);
}

// Round 7
// 561.106 us; speedup vs baseline: 4.1001x; 1.2070x over previous
//
#include <hip/hip_runtime.h>
#include <math.h>

#define NN 50000
#define EE 800000
#define OO 4
#define CC 64
#define KDD 16
#define KEYDD 128
#define CH 8  // unrolled edges per chunk in mega (MLP depth; arrays fully unrolled)

__device__ __forceinline__ float wave_sum64(float v) {
  for (int off = 32; off > 0; off >>= 1) v += __shfl_xor(v, off, 64);
  return v;
}

// Full-wave (64-lane) sum via DPP (pure VALU, no LDS/ds_bpermute).
// row_shr:1/2/4/8 -> per-16-row sums in lanes 15/31/47/63;
// row_bcast:15 (rows 1,3) + row_bcast:31 (rows 2,3) -> lane 63 = total.
// Result returned as wave-uniform scalar via readlane(63).
__device__ __forceinline__ float wave_red_sum(float v) {
  int x;
  x = __builtin_amdgcn_update_dpp(0, __float_as_int(v), 0x111, 0xf, 0xf, false);
  v += __int_as_float(x);
  x = __builtin_amdgcn_update_dpp(0, __float_as_int(v), 0x112, 0xf, 0xf, false);
  v += __int_as_float(x);
  x = __builtin_amdgcn_update_dpp(0, __float_as_int(v), 0x114, 0xf, 0xf, false);
  v += __int_as_float(x);
  x = __builtin_amdgcn_update_dpp(0, __float_as_int(v), 0x118, 0xf, 0xf, false);
  v += __int_as_float(x);
  x = __builtin_amdgcn_update_dpp(0, __float_as_int(v), 0x142, 0xa, 0xf, false);
  v += __int_as_float(x);
  x = __builtin_amdgcn_update_dpp(0, __float_as_int(v), 0x143, 0xc, 0xf, false);
  v += __int_as_float(x);
  return __int_as_float(__builtin_amdgcn_readlane(__float_as_int(v), 63));
}

// P0 (blocks 0..15): Mt[c2*64+c1] = sum_k keyW[k,c1]*qryW[k,c2]  (TRANSPOSED so
// mega's per-c2 read is one coalesced 256B segment). Block 16: aVec/bVec/c0/fk
// (fk pre-scaled by 0.25).
__global__ void prep_kernel(const float* __restrict__ keyW, const float* __restrict__ keyB,
                            const float* __restrict__ qryW, const float* __restrict__ qryB,
                            const float* __restrict__ fkb, const float* __restrict__ fkw,
                            float* __restrict__ Mt, float* __restrict__ aVec,
                            float* __restrict__ bVec, float* __restrict__ c0,
                            float* __restrict__ fk) {
  __shared__ float qw[KEYDD * CC];   // 32 KB
  __shared__ float kws[KEYDD * 4];   // 2 KB
  int t = threadIdx.x, b = blockIdx.x;
  if (b < 16) {
    for (int i = t; i < KEYDD * CC; i += 256) qw[i] = qryW[i];
    for (int i = t; i < KEYDD * 4; i += 256) {
      int k = i >> 2, c1l = i & 3;
      kws[i] = keyW[k * CC + b * 4 + c1l];
    }
    __syncthreads();
    int c1l = t >> 6, c2 = t & 63;
    float s = 0.f;
    #pragma unroll 8
    for (int k = 0; k < KEYDD; ++k)
      s = fmaf(kws[k * 4 + c1l], qw[k * CC + c2], s);
    Mt[c2 * CC + b * 4 + c1l] = s;
  } else {
    if (t < CC) {
      float sa = 0.f, sb = 0.f;
      for (int k = 0; k < KEYDD; ++k) {
        sa = fmaf(keyB[k], qryW[k * CC + t], sa);
        sb = fmaf(qryB[k], keyW[k * CC + t], sb);
      }
      aVec[t] = sa; bVec[t] = sb;
    }
    if (t == 0) {
      float s = 0.f;
      for (int k = 0; k < KEYDD; ++k) s = fmaf(keyB[k], qryB[k], s);
      c0[0] = s;
    }
    for (int idx = t; idx < OO * OO * CC; idx += 256) {
      int p = idx >> 8, rem = idx & 255;
      int o = rem >> 6, c = rem & 63;
      float s = 0.f;
      #pragma unroll
      for (int kd = 0; kd < KDD; ++kd)
        s = fmaf(fkb[(p * OO + o) * KDD + kd], fkw[c * KDD + kd], s);
      fk[idx] = 0.25f * s;  // fold the 1/O normalization here
    }
  }
}

// K2a: CSR degree counts
__global__ void count_kernel(const int* __restrict__ ei, int* __restrict__ counts) {
  int e = blockIdx.x * 256 + threadIdx.x;
  if (e < EE) atomicAdd(&counts[ei[EE + e]], 1);
}

// K2b: single-block chunked exclusive scan
__global__ void scan_kernel(const int* __restrict__ counts, int* __restrict__ offsets, int n) {
  __shared__ int sums[1024];
  int t = threadIdx.x;
  int chunk = (n + 1023) >> 10;
  int begin = t * chunk;
  int finish = min(begin + chunk, n);
  int s = 0;
  for (int i = begin; i < finish; ++i) s += counts[i];
  sums[t] = s;
  __syncthreads();
  for (int off = 1; off < 1024; off <<= 1) {
    int v = sums[t];
    int w = (t >= off) ? sums[t - off] : 0;
    __syncthreads();
    sums[t] = v + w;
    __syncthreads();
  }
  int excl = (t == 0) ? 0 : sums[t - 1];
  for (int i = begin; i < finish; ++i) {
    offsets[i] = excl;
    excl += counts[i];
  }
  if (t == 1023) offsets[n] = excl;
}

// K2c: fill CSR as packed (src<<32 | eid) pairs; reuses counts as cursor.
__global__ void fill_kernel(const int* __restrict__ ei, const int* __restrict__ offsets,
                            int* __restrict__ counts, long long* __restrict__ pairs) {
  int e = blockIdx.x * 256 + threadIdx.x;
  if (e < EE) {
    int d = ei[EE + e];
    int r = atomicSub(&counts[d], 1) - 1;
    int pos = offsets[d] + r;
    pairs[pos] = ((long long)ei[e] << 32) | (unsigned)e;
  }
}

// K3: MEGA — per node; computes its own ub (node_proj fused), then wave=o owns
// its (n,o) softmax+aggregation end-to-end, barrier-free in the edge loop.
// Per chunk of 8 edges: ONE packed pair load + v_readlane (lane-literal) makes
// eid/src wave-uniform SGPRs -> x gather is SGPR-base+lane-offset, kb offsets
// are SALU, and there are NO ds_bpermute shfls. Logit reduce via DPP (VALU).
// NOTE: no min-waves launch_bounds — (256,8) caused VGPR spill (R4: 4x regress).
__global__ __launch_bounds__(256) void mega_kernel(
    const float* __restrict__ x, const float* __restrict__ Mt,
    const float* __restrict__ aVec, const float* __restrict__ bVec,
    const float* __restrict__ c0p, const float* __restrict__ kb,
    const float* __restrict__ kW, const int* __restrict__ offsets,
    const long long* __restrict__ pairs, const float* __restrict__ fkg,
    const float* __restrict__ bias, float* __restrict__ out) {
  __shared__ float xs[OO * CC];
  __shared__ float x1[OO * CC];
  int n = blockIdx.x;
  int t = threadIdx.x;
  int o = __builtin_amdgcn_readfirstlane(t >> 6);
  int c = t & 63;
  const float scale = 0.08838834764831845f;  // 1/sqrt(128)
  int js = offsets[n], je = offsets[n + 1];
  int deg = je - js;

  // ---- fused node_proj: own x rows -> LDS; ub = Mt^T x + bVec; base from aVec
  float xown = x[(size_t)n * (OO * CC) + t];
  xs[t] = xown;
  __syncthreads();
  float ubr = 0.f;
  #pragma unroll 8
  for (int c2 = 0; c2 < CC; ++c2)
    ubr = fmaf(Mt[c2 * CC + c], xs[o * CC + c2], ubr);
  ubr += bVec[c];
  float base = (wave_red_sum(aVec[c] * xown) + c0p[0]) * scale;

  const float4* kwp = reinterpret_cast<const float4*>(kW + c * KDD);
  float4 kw0 = kwp[0], kw1 = kwp[1], kw2 = kwp[2], kw3 = kwp[3];

  float m = -INFINITY, S = 0.f, acc = 0.f;
  int lane8 = c & 7;
  int obase = o * KDD;

  for (int cs = 0; cs < deg; cs += CH) {
    int cl = min(CH, deg - cs);
    long long pr = pairs[js + cs + min(lane8, cl - 1)];
    int e_v = (int)((unsigned)pr);      // low 32: edge id
    int s_v = (int)(pr >> 32);          // high 32: src node
    float xv[CH], lg[CH], kv[CH];
    // 1) all 8 x-row gathers in flight (uniform row base via readlane)
    #pragma unroll
    for (int j = 0; j < CH; ++j) {
      int sj = __builtin_amdgcn_readlane(s_v, j);
      xv[j] = x[(size_t)(sj * OO + o) * CC + c];
    }
    // 2) kb slices via scalar loads (SGPR offset) + dot with register kW row
    #pragma unroll
    for (int j = 0; j < CH; ++j) {
      int ej = __builtin_amdgcn_readlane(e_v, j);
      const float4* bp = reinterpret_cast<const float4*>(kb + ej * (OO * KDD) + obase);
      float4 b0 = bp[0], b1 = bp[1], b2 = bp[2], b3 = bp[3];
      float kva = 0.f, kvb = 0.f;
      kva = fmaf(b0.x, kw0.x, kva); kva = fmaf(b0.y, kw0.y, kva);
      kva = fmaf(b0.z, kw0.z, kva); kva = fmaf(b0.w, kw0.w, kva);
      kva = fmaf(b1.x, kw1.x, kva); kva = fmaf(b1.y, kw1.y, kva);
      kva = fmaf(b1.z, kw1.z, kva); kva = fmaf(b1.w, kw1.w, kva);
      kvb = fmaf(b2.x, kw2.x, kvb); kvb = fmaf(b2.y, kw2.y, kvb);
      kvb = fmaf(b2.z, kw2.z, kvb); kvb = fmaf(b2.w, kw2.w, kvb);
      kvb = fmaf(b3.x, kw3.x, kvb); kvb = fmaf(b3.y, kw3.y, kvb);
      kvb = fmaf(b3.z, kw3.z, kvb); kvb = fmaf(b3.w, kw3.w, kvb);
      kv[j] = kva + kvb;
    }
    // 3) logits: DPP reduce (VALU-only), result wave-uniform
    #pragma unroll
    for (int j = 0; j < CH; ++j) {
      float p = wave_red_sum(xv[j] * ubr);
      lg[j] = (j < cl) ? fmaf(p, scale, base) : -INFINITY;
    }
    // 4) chunk max, online merge
    float cm = lg[0];
    #pragma unroll
    for (int j = 1; j < CH; ++j) cm = fmaxf(cm, lg[j]);
    float mn = fmaxf(m, cm);
    float rsc = __expf(m - mn);  // first chunk: exp(-inf)=0
    S *= rsc; acc *= rsc; m = mn;
    // 5) exp + aggregate (tail lanes: ev = exp(-inf) = 0)
    #pragma unroll
    for (int j = 0; j < CH; ++j) {
      float ev = __expf(lg[j] - m);
      S += ev;
      acc = fmaf(ev * kv[j], xv[j], acc);
    }
  }
  float invd = 1.0f / (S + 1e-6f);
  x1[t] = acc * invd;
  __syncthreads();
  // fiber mix: out[n,p=o,c] = sum_oo x1[oo,c]*fk[o,oo,c] + bias[c]  (0.25 in fk)
  float s2s = 0.f;
  #pragma unroll
  for (int oo = 0; oo < OO; ++oo)
    s2s = fmaf(x1[oo * CC + c], fkg[o * (OO * CC) + oo * CC + c], s2s);
  out[(size_t)n * (OO * CC) + t] = s2s + bias[c];
}

extern "C" void kernel_launch(void* const* d_in, const int* in_sizes, int n_in,
                              void* d_out, int out_size, void* d_ws, size_t ws_size,
                              hipStream_t stream) {
  const float* x    = (const float*)d_in[0];
  const float* kb   = (const float*)d_in[1];
  const float* fkb  = (const float*)d_in[2];
  const int*   ei   = (const int*)d_in[3];
  const float* kW   = (const float*)d_in[4];
  const float* fkW  = (const float*)d_in[5];
  const float* keyW = (const float*)d_in[6];
  const float* keyB = (const float*)d_in[7];
  const float* qryW = (const float*)d_in[8];
  const float* qryB = (const float*)d_in[9];
  const float* bias = (const float*)d_in[10];
  float* out = (float*)d_out;

  float* wsf  = (float*)d_ws;
  float* Mt   = wsf;                          // 4096
  float* aVec = Mt + 4096;                    // 64
  float* bVec = aVec + 64;                    // 64
  float* c0   = bVec + 64;                    // 1 (+63 pad)
  float* fk   = c0 + 64;                      // 1024
  // total 5312 floats = 21248 B (8B-aligned)
  long long* pairs = (long long*)(fk + 1024);   // EE * 8B
  int* counts    = (int*)(pairs + EE);          // 50000
  int* offsets   = counts + NN;                 // 50001

  hipMemsetAsync(counts, 0, (size_t)NN * sizeof(int), stream);

  prep_kernel<<<17, 256, 0, stream>>>(keyW, keyB, qryW, qryB, fkb, fkW, Mt, aVec, bVec, c0, fk);
  count_kernel<<<(EE + 255) / 256, 256, 0, stream>>>(ei, counts);
  scan_kernel<<<1, 1024, 0, stream>>>(counts, offsets, NN);
  fill_kernel<<<(EE + 255) / 256, 256, 0, stream>>>(ei, offsets, counts, pairs);
  mega_kernel<<<NN, 256, 0, stream>>>(x, Mt, aVec, bVec, c0, kb, kW, offsets, pairs,
                                      fk, bias, out);
}

// Round 8
// 557.718 us; speedup vs baseline: 4.1250x; 1.0061x over previous
//
#include <hip/hip_runtime.h>
#include <math.h>

#define NN 50000
#define EE 800000
#define OO 4
#define CC 64
#define KDD 16
#define KEYDD 128
#define CH 16  // gather window per chunk (two 8-edge compute sub-blocks)

__device__ __forceinline__ float wave_sum64(float v) {
  for (int off = 32; off > 0; off >>= 1) v += __shfl_xor(v, off, 64);
  return v;
}

// Full-wave (64-lane) sum via DPP (pure VALU, no LDS/ds_bpermute).
__device__ __forceinline__ float wave_red_sum(float v) {
  int x;
  x = __builtin_amdgcn_update_dpp(0, __float_as_int(v), 0x111, 0xf, 0xf, false);
  v += __int_as_float(x);
  x = __builtin_amdgcn_update_dpp(0, __float_as_int(v), 0x112, 0xf, 0xf, false);
  v += __int_as_float(x);
  x = __builtin_amdgcn_update_dpp(0, __float_as_int(v), 0x114, 0xf, 0xf, false);
  v += __int_as_float(x);
  x = __builtin_amdgcn_update_dpp(0, __float_as_int(v), 0x118, 0xf, 0xf, false);
  v += __int_as_float(x);
  x = __builtin_amdgcn_update_dpp(0, __float_as_int(v), 0x142, 0xa, 0xf, false);
  v += __int_as_float(x);
  x = __builtin_amdgcn_update_dpp(0, __float_as_int(v), 0x143, 0xc, 0xf, false);
  v += __int_as_float(x);
  return __int_as_float(__builtin_amdgcn_readlane(__float_as_int(v), 63));
}

// bare v_exp_f32: D = 2^x  (exp in log2 domain; saves the ln2 v_mul of __expf)
__device__ __forceinline__ float exp2_fast(float x) {
  float r;
  asm("v_exp_f32 %0, %1" : "=v"(r) : "v"(x));
  return r;
}

// P0 (blocks 0..15): Mt[c2*64+c1] = sum_k keyW[k,c1]*qryW[k,c2] (transposed so
// mega's per-c2 read is one coalesced 256B segment). Block 16: aVec/bVec/c0/fk
// (fk pre-scaled by 0.25).
__global__ void prep_kernel(const float* __restrict__ keyW, const float* __restrict__ keyB,
                            const float* __restrict__ qryW, const float* __restrict__ qryB,
                            const float* __restrict__ fkb, const float* __restrict__ fkw,
                            float* __restrict__ Mt, float* __restrict__ aVec,
                            float* __restrict__ bVec, float* __restrict__ c0,
                            float* __restrict__ fk) {
  __shared__ float qw[KEYDD * CC];   // 32 KB
  __shared__ float kws[KEYDD * 4];   // 2 KB
  int t = threadIdx.x, b = blockIdx.x;
  if (b < 16) {
    for (int i = t; i < KEYDD * CC; i += 256) qw[i] = qryW[i];
    for (int i = t; i < KEYDD * 4; i += 256) {
      int k = i >> 2, c1l = i & 3;
      kws[i] = keyW[k * CC + b * 4 + c1l];
    }
    __syncthreads();
    int c1l = t >> 6, c2 = t & 63;
    float s = 0.f;
    #pragma unroll 8
    for (int k = 0; k < KEYDD; ++k)
      s = fmaf(kws[k * 4 + c1l], qw[k * CC + c2], s);
    Mt[c2 * CC + b * 4 + c1l] = s;
  } else {
    if (t < CC) {
      float sa = 0.f, sb = 0.f;
      for (int k = 0; k < KEYDD; ++k) {
        sa = fmaf(keyB[k], qryW[k * CC + t], sa);
        sb = fmaf(qryB[k], keyW[k * CC + t], sb);
      }
      aVec[t] = sa; bVec[t] = sb;
    }
    if (t == 0) {
      float s = 0.f;
      for (int k = 0; k < KEYDD; ++k) s = fmaf(keyB[k], qryB[k], s);
      c0[0] = s;
    }
    for (int idx = t; idx < OO * OO * CC; idx += 256) {
      int p = idx >> 8, rem = idx & 255;
      int o = rem >> 6, c = rem & 63;
      float s = 0.f;
      #pragma unroll
      for (int kd = 0; kd < KDD; ++kd)
        s = fmaf(fkb[(p * OO + o) * KDD + kd], fkw[c * KDD + kd], s);
      fk[idx] = 0.25f * s;  // fold the 1/O normalization here
    }
  }
}

// K2a: CSR degree counts
__global__ void count_kernel(const int* __restrict__ ei, int* __restrict__ counts) {
  int e = blockIdx.x * 256 + threadIdx.x;
  if (e < EE) atomicAdd(&counts[ei[EE + e]], 1);
}

// K2b: single-block chunked exclusive scan
__global__ void scan_kernel(const int* __restrict__ counts, int* __restrict__ offsets, int n) {
  __shared__ int sums[1024];
  int t = threadIdx.x;
  int chunk = (n + 1023) >> 10;
  int begin = t * chunk;
  int finish = min(begin + chunk, n);
  int s = 0;
  for (int i = begin; i < finish; ++i) s += counts[i];
  sums[t] = s;
  __syncthreads();
  for (int off = 1; off < 1024; off <<= 1) {
    int v = sums[t];
    int w = (t >= off) ? sums[t - off] : 0;
    __syncthreads();
    sums[t] = v + w;
    __syncthreads();
  }
  int excl = (t == 0) ? 0 : sums[t - 1];
  for (int i = begin; i < finish; ++i) {
    offsets[i] = excl;
    excl += counts[i];
  }
  if (t == 1023) offsets[n] = excl;
}

// K2c: fill CSR as packed (src<<32 | eid) pairs; reuses counts as cursor.
__global__ void fill_kernel(const int* __restrict__ ei, const int* __restrict__ offsets,
                            int* __restrict__ counts, long long* __restrict__ pairs) {
  int e = blockIdx.x * 256 + threadIdx.x;
  if (e < EE) {
    int d = ei[EE + e];
    int r = atomicSub(&counts[d], 1) - 1;
    int pos = offsets[d] + r;
    pairs[pos] = ((long long)ei[e] << 32) | (unsigned)e;
  }
}

// kv = dot16(kb[ej, o, :], kW[c, :])  — kb slice wave-uniform (SGPR path)
__device__ __forceinline__ float kv_dot(const float* __restrict__ kb, int ej, int obase,
                                        float4 kw0, float4 kw1, float4 kw2, float4 kw3) {
  const float4* bp = reinterpret_cast<const float4*>(kb + ej * (OO * KDD) + obase);
  float4 b0 = bp[0], b1 = bp[1], b2 = bp[2], b3 = bp[3];
  float kva = 0.f, kvb = 0.f;
  kva = fmaf(b0.x, kw0.x, kva); kva = fmaf(b0.y, kw0.y, kva);
  kva = fmaf(b0.z, kw0.z, kva); kva = fmaf(b0.w, kw0.w, kva);
  kva = fmaf(b1.x, kw1.x, kva); kva = fmaf(b1.y, kw1.y, kva);
  kva = fmaf(b1.z, kw1.z, kva); kva = fmaf(b1.w, kw1.w, kva);
  kvb = fmaf(b2.x, kw2.x, kvb); kvb = fmaf(b2.y, kw2.y, kvb);
  kvb = fmaf(b2.z, kw2.z, kvb); kvb = fmaf(b2.w, kw2.w, kvb);
  kvb = fmaf(b3.x, kw3.x, kvb); kvb = fmaf(b3.y, kw3.y, kvb);
  kvb = fmaf(b3.z, kw3.z, kvb); kvb = fmaf(b3.w, kw3.w, kvb);
  return kva + kvb;
}

// K3: MEGA — per node; fused ub compute, then wave=o owns its (n,o) softmax +
// aggregation end-to-end, barrier-free in the edge loop.
// Per chunk: 16 x-row gathers issued up front (deep MLP), next chunk's pairs
// prefetched before softmax; compute in two 8-edge sub-blocks (register-light,
// sub1 skipped wave-uniformly when cl<=8). Softmax runs in log2 domain
// (v_exp_f32 directly). Chunk-0 pairs load issues BEFORE the ub compute so the
// 64-FMA ub chain hides its latency.
// NOTE: no min-waves launch_bounds — (256,8) caused VGPR spill (R4: 4x regress).
__global__ __launch_bounds__(256) void mega_kernel(
    const float* __restrict__ x, const float* __restrict__ Mt,
    const float* __restrict__ aVec, const float* __restrict__ bVec,
    const float* __restrict__ c0p, const float* __restrict__ kb,
    const float* __restrict__ kW, const int* __restrict__ offsets,
    const long long* __restrict__ pairs, const float* __restrict__ fkg,
    const float* __restrict__ bias, float* __restrict__ out) {
  __shared__ float xs[OO * CC];
  __shared__ float x1[OO * CC];
  int n = blockIdx.x;
  int t = threadIdx.x;
  int o = __builtin_amdgcn_readfirstlane(t >> 6);
  int c = t & 63;
  const float scale2 = 0.12751541050862828f;  // (1/sqrt(128)) * log2(e)
  int js = offsets[n], je = offsets[n + 1];
  int deg = je - js;

  float xown = x[(size_t)n * (OO * CC) + t];
  xs[t] = xown;
  __syncthreads();

  int lane16 = c & 15;
  long long pr = 0;
  if (deg > 0) pr = pairs[js + min(lane16, deg - 1)];  // chunk-0 head, in flight early

  // ub = Mt^T x + bVec (independent of pr -> hides the pairs-load latency)
  float ubr = 0.f;
  #pragma unroll 8
  for (int c2 = 0; c2 < CC; ++c2)
    ubr = fmaf(Mt[c2 * CC + c], xs[o * CC + c2], ubr);
  ubr += bVec[c];
  float base2 = (wave_red_sum(aVec[c] * xown) + c0p[0]) * scale2;

  const float4* kwp = reinterpret_cast<const float4*>(kW + c * KDD);
  float4 kw0 = kwp[0], kw1 = kwp[1], kw2 = kwp[2], kw3 = kwp[3];
  int obase = o * KDD;

  float m2 = -INFINITY, S = 0.f, acc = 0.f;

  for (int cs = 0; cs < deg; cs += CH) {
    int cl = deg - cs; if (cl > CH) cl = CH;  // wave-uniform
    int e_v = (int)((unsigned long long)pr & 0xffffffffu);
    int s_v = (int)(pr >> 32);
    float xv[CH];
    // 1) all 16 x-row gathers in flight (uniform row base via readlane)
    #pragma unroll
    for (int j = 0; j < CH; ++j) {
      int sj = __builtin_amdgcn_readlane(s_v, j);
      xv[j] = x[(size_t)(sj * OO + o) * CC + c];
    }
    // 2) prefetch next chunk's pairs (head of next dependency chain)
    int ns = cs + CH;
    if (ns < deg) {
      int ncl = deg - ns;
      pr = pairs[js + ns + min(lane16, ncl - 1)];
    }
    // 3) two 8-edge compute sub-blocks
    #define SUB_BLOCK(J0)                                                      \
    {                                                                          \
      float kv[8], lg[8];                                                      \
      _Pragma("unroll")                                                        \
      for (int j = 0; j < 8; ++j) {                                            \
        int ej = __builtin_amdgcn_readlane(e_v, (J0) + j);                     \
        kv[j] = kv_dot(kb, ej, obase, kw0, kw1, kw2, kw3);                     \
      }                                                                        \
      _Pragma("unroll")                                                        \
      for (int j = 0; j < 8; ++j) {                                            \
        float p = wave_red_sum(xv[(J0) + j] * ubr);                            \
        lg[j] = ((J0) + j < cl) ? fmaf(p, scale2, base2) : -INFINITY;          \
      }                                                                        \
      float cm = fmaxf(fmaxf(fmaxf(lg[0], lg[1]), fmaxf(lg[2], lg[3])),        \
                       fmaxf(fmaxf(lg[4], lg[5]), fmaxf(lg[6], lg[7])));       \
      float mn = fmaxf(m2, cm);                                                \
      float rsc = exp2_fast(m2 - mn);                                          \
      S *= rsc; acc *= rsc; m2 = mn;                                           \
      _Pragma("unroll")                                                        \
      for (int j = 0; j < 8; ++j) {                                            \
        float ev = exp2_fast(lg[j] - m2);                                      \
        S += ev;                                                               \
        acc = fmaf(ev * kv[j], xv[(J0) + j], acc);                             \
      }                                                                        \
    }
    SUB_BLOCK(0)
    if (cl > 8) SUB_BLOCK(8)
    #undef SUB_BLOCK
  }
  float invd = 1.0f / (S + 1e-6f);
  x1[t] = acc * invd;
  __syncthreads();
  // fiber mix: out[n,p=o,c] = sum_oo x1[oo,c]*fk[o,oo,c] + bias[c]  (0.25 in fk)
  float s2s = 0.f;
  #pragma unroll
  for (int oo = 0; oo < OO; ++oo)
    s2s = fmaf(x1[oo * CC + c], fkg[o * (OO * CC) + oo * CC + c], s2s);
  out[(size_t)n * (OO * CC) + t] = s2s + bias[c];
}

extern "C" void kernel_launch(void* const* d_in, const int* in_sizes, int n_in,
                              void* d_out, int out_size, void* d_ws, size_t ws_size,
                              hipStream_t stream) {
  const float* x    = (const float*)d_in[0];
  const float* kb   = (const float*)d_in[1];
  const float* fkb  = (const float*)d_in[2];
  const int*   ei   = (const int*)d_in[3];
  const float* kW   = (const float*)d_in[4];
  const float* fkW  = (const float*)d_in[5];
  const float* keyW = (const float*)d_in[6];
  const float* keyB = (const float*)d_in[7];
  const float* qryW = (const float*)d_in[8];
  const float* qryB = (const float*)d_in[9];
  const float* bias = (const float*)d_in[10];
  float* out = (float*)d_out;

  float* wsf  = (float*)d_ws;
  float* Mt   = wsf;                          // 4096
  float* aVec = Mt + 4096;                    // 64
  float* bVec = aVec + 64;                    // 64
  float* c0   = bVec + 64;                    // 1 (+63 pad)
  float* fk   = c0 + 64;                      // 1024
  // total 5312 floats = 21248 B (8B-aligned)
  long long* pairs = (long long*)(fk + 1024);   // EE * 8B
  int* counts    = (int*)(pairs + EE);          // 50000
  int* offsets   = counts + NN;                 // 50001

  hipMemsetAsync(counts, 0, (size_t)NN * sizeof(int), stream);

  prep_kernel<<<17, 256, 0, stream>>>(keyW, keyB, qryW, qryB, fkb, fkW, Mt, aVec, bVec, c0, fk);
  count_kernel<<<(EE + 255) / 256, 256, 0, stream>>>(ei, counts);
  scan_kernel<<<1, 1024, 0, stream>>>(counts, offsets, NN);
  fill_kernel<<<(EE + 255) / 256, 256, 0, stream>>>(ei, offsets, counts, pairs);
  mega_kernel<<<NN, 256, 0, stream>>>(x, Mt, aVec, bVec, c0, kb, kW, offsets, pairs,
                                      fk, bias, out);
}